// Round 1
// baseline (1284.081 us; speedup 1.0000x reference)
//
#include <hip/hip_runtime.h>
#include <hip/hip_bf16.h>

#define NN 100000
#define NE 600000
#define HH 128
#define NB 4

typedef __attribute__((ext_vector_type(8))) short bf16x8;
typedef __attribute__((ext_vector_type(4))) float f32x4;
typedef __attribute__((ext_vector_type(4))) float vfloat4;

// round-to-nearest-even f32 -> bf16 bits (inputs are finite)
static __device__ __forceinline__ short f2bf(float f) {
  unsigned u = __float_as_uint(f);
  unsigned r = (u + 0x7fffu + ((u >> 16) & 1u)) >> 16;
  return (short)r;
}

static __device__ __forceinline__ float bf2f(short s) {
  unsigned u = (unsigned)(unsigned short)s;
  return __uint_as_float(u << 16);
}

// Build combined bf16 weight matrix Bt[col][k], col in [0,640), k in [0,128).
// col < 512: Bt[col][k] = V[b=col>>7][i=k][o=col&127]
// col >=512: Bt[col][k] = loopW[i=k][o=col-512]
__global__ void build_bt(const float* __restrict__ V, const float* __restrict__ loopW,
                         short* __restrict__ Bt)
{
  int idx = blockIdx.x * blockDim.x + threadIdx.x;
  if (idx >= 640 * 128) return;
  int col = idx >> 7;
  int k = idx & 127;
  float v;
  if (col < 512) {
    int b = col >> 7;
    int o = col & 127;
    v = V[((size_t)b * HH + k) * HH + o];
  } else {
    v = loopW[(size_t)k * HH + (col - 512)];
  }
  Bt[(size_t)col * HH + k] = f2bf(v);
}

// Fused GEMM: [N,128] @ [128,640] with MFMA 16x16x32 bf16.
// Writes hb (bf16, cols 0..511) and outInit = bias + h@loopW (fp32, cols 512..639).
// RELU=1 applies relu to A on load (layer-2 consumes pre-activation layer-1 output).
template<int RELU>
__global__ __launch_bounds__(256) void gemm_layer(
    const float* __restrict__ A,        // [N,128] fp32
    const short* __restrict__ Bt,       // [640][128] bf16 bits
    const float* __restrict__ bias,     // [128]
    short* __restrict__ hb,             // [N,512] bf16 bits
    float* __restrict__ outInit)        // [N,128] fp32
{
  const int wave = threadIdx.x >> 6;
  const int lane = threadIdx.x & 63;
  const int row_base = blockIdx.x * 64 + wave * 16;
  if (row_base >= NN) return;
  const int r = lane & 15;   // A row within tile / D col within tile
  const int g = lane >> 4;   // k-group

  // A fragments for all 4 K-steps (K=128 = 4 x 32)
  bf16x8 afrag[4];
  const float* arow = A + (size_t)(row_base + r) * HH;
#pragma unroll
  for (int ks = 0; ks < 4; ++ks) {
    const vfloat4* ap = reinterpret_cast<const vfloat4*>(arow + ks * 32 + g * 8);
    vfloat4 v0 = ap[0];
    vfloat4 v1 = ap[1];
    bf16x8 af;
#pragma unroll
    for (int j = 0; j < 4; ++j) {
      float x0 = v0[j], x1 = v1[j];
      if (RELU) { x0 = fmaxf(x0, 0.f); x1 = fmaxf(x1, 0.f); }
      af[j] = f2bf(x0);
      af[j + 4] = f2bf(x1);
    }
    afrag[ks] = af;
  }

  const bf16x8* btv = reinterpret_cast<const bf16x8*>(Bt);
#pragma unroll 1
  for (int ct = 0; ct < 40; ++ct) {
    f32x4 acc = {0.f, 0.f, 0.f, 0.f};
#pragma unroll
    for (int ks = 0; ks < 4; ++ks) {
      bf16x8 bfr = btv[(size_t)(ct * 16 + r) * 16 + ks * 4 + g];
      acc = __builtin_amdgcn_mfma_f32_16x16x32_bf16(afrag[ks], bfr, acc, 0, 0, 0);
    }
    // D mapping: col = lane&15 (=r), row = (lane>>4)*4 + rr  [verified layout]
    if (ct < 32) {
#pragma unroll
      for (int rr = 0; rr < 4; ++rr) {
        int row = row_base + g * 4 + rr;
        hb[(size_t)row * 512 + ct * 16 + r] = f2bf(acc[rr]);
      }
    } else {
      int o = ct * 16 + r - 512;
      float bs = bias[o];
#pragma unroll
      for (int rr = 0; rr < 4; ++rr) {
        int row = row_base + g * 4 + rr;
        outInit[(size_t)row * HH + o] = acc[rr] + bs;
      }
    }
  }
}

// One wave per edge: gather hb[src] (512 bf16), scale by comp[etype][b],
// butterfly-reduce over the 4 basis groups, atomically scatter 128 fp32 to out[dst].
__global__ __launch_bounds__(256) void edge_scatter(
    const int* __restrict__ src, const int* __restrict__ dst, const int* __restrict__ ety,
    const float* __restrict__ comp,   // [R,B]
    const short* __restrict__ hb,     // [N,512] bf16 bits
    float* __restrict__ out)          // [N,128] fp32 (pre-initialized)
{
  const int wid = (int)((blockIdx.x * blockDim.x + threadIdx.x) >> 6);
  if (wid >= NE) return;
  const int lane = threadIdx.x & 63;
  const int s = src[wid];
  const int d = dst[wid];
  const int e = ety[wid];
  const int b = lane >> 4;
  const float c = comp[e * NB + b];

  const bf16x8* hp = reinterpret_cast<const bf16x8*>(hb + (size_t)s * 512);
  bf16x8 hv = hp[lane];
  float m0 = bf2f(hv[0]) * c, m1 = bf2f(hv[1]) * c;
  float m2 = bf2f(hv[2]) * c, m3 = bf2f(hv[3]) * c;
  float m4 = bf2f(hv[4]) * c, m5 = bf2f(hv[5]) * c;
  float m6 = bf2f(hv[6]) * c, m7 = bf2f(hv[7]) * c;

  m0 += __shfl_xor(m0, 16); m1 += __shfl_xor(m1, 16);
  m2 += __shfl_xor(m2, 16); m3 += __shfl_xor(m3, 16);
  m4 += __shfl_xor(m4, 16); m5 += __shfl_xor(m5, 16);
  m6 += __shfl_xor(m6, 16); m7 += __shfl_xor(m7, 16);
  m0 += __shfl_xor(m0, 32); m1 += __shfl_xor(m1, 32);
  m2 += __shfl_xor(m2, 32); m3 += __shfl_xor(m3, 32);
  m4 += __shfl_xor(m4, 32); m5 += __shfl_xor(m5, 32);
  m6 += __shfl_xor(m6, 32); m7 += __shfl_xor(m7, 32);

  // each basis-replica lane writes 2 distinct elements (128 unique atomics/edge)
  float x0 = (b == 0) ? m0 : (b == 1) ? m2 : (b == 2) ? m4 : m6;
  float x1 = (b == 0) ? m1 : (b == 1) ? m3 : (b == 2) ? m5 : m7;
  float* orow = out + (size_t)d * HH + (lane & 15) * 8 + 2 * b;
  unsafeAtomicAdd(orow, x0);
  unsafeAtomicAdd(orow + 1, x1);
}

extern "C" void kernel_launch(void* const* d_in, const int* in_sizes, int n_in,
                              void* d_out, int out_size, void* d_ws, size_t ws_size,
                              hipStream_t stream)
{
  const int*   srcp  = (const int*)d_in[1];
  const int*   dstp  = (const int*)d_in[2];
  const int*   etp   = (const int*)d_in[3];
  const float* emb   = (const float*)d_in[4];
  const float* V1    = (const float*)d_in[5];
  const float* comp1 = (const float*)d_in[6];
  const float* loop1 = (const float*)d_in[7];
  const float* bias1 = (const float*)d_in[8];
  const float* V2    = (const float*)d_in[9];
  const float* comp2 = (const float*)d_in[10];
  const float* loop2 = (const float*)d_in[11];
  const float* bias2 = (const float*)d_in[12];
  float* out = (float*)d_out;

  char* ws = (char*)d_ws;
  short* Bt1  = (short*)ws;                              // 163,840 B
  short* Bt2  = (short*)(ws + 163840);                   // 163,840 B
  short* hb   = (short*)(ws + 327680);                   // 102,400,000 B
  float* out1 = (float*)(ws + 327680 + 102400000);       // 51,200,000 B

  const int gemm_blocks = (NN + 63) / 64;
  const int edge_blocks = (NE + 3) / 4;

  hipLaunchKernelGGL(build_bt, dim3(320), dim3(256), 0, stream, V1, loop1, Bt1);
  hipLaunchKernelGGL(build_bt, dim3(320), dim3(256), 0, stream, V2, loop2, Bt2);

  // Layer 1: h = embedding (no relu on load)
  hipLaunchKernelGGL((gemm_layer<0>), dim3(gemm_blocks), dim3(256), 0, stream,
                     emb, Bt1, bias1, hb, out1);
  hipLaunchKernelGGL(edge_scatter, dim3(edge_blocks), dim3(256), 0, stream,
                     srcp, dstp, etp, comp1, hb, out1);

  // Layer 2: A = out1 with relu fused into load; writes into d_out
  hipLaunchKernelGGL((gemm_layer<1>), dim3(gemm_blocks), dim3(256), 0, stream,
                     out1, Bt2, bias2, hb, out);
  hipLaunchKernelGGL(edge_scatter, dim3(edge_blocks), dim3(256), 0, stream,
                     srcp, dstp, etp, comp2, hb, out);
}

// Round 2
// 675.846 us; speedup vs baseline: 1.9000x; 1.9000x over previous
//
#include <hip/hip_runtime.h>
#include <hip/hip_bf16.h>

#define NN 100000
#define NE 600000
#define HH 128
#define NB 4

typedef __attribute__((ext_vector_type(8))) short bf16x8;
typedef __attribute__((ext_vector_type(4))) float f32x4;
typedef __attribute__((ext_vector_type(4))) float vfloat4;
typedef __attribute__((ext_vector_type(2))) float vfloat2;

// round-to-nearest-even f32 -> bf16 bits (inputs are finite)
static __device__ __forceinline__ short f2bf(float f) {
  unsigned u = __float_as_uint(f);
  unsigned r = (u + 0x7fffu + ((u >> 16) & 1u)) >> 16;
  return (short)r;
}

static __device__ __forceinline__ float bf2f(short s) {
  unsigned u = (unsigned)(unsigned short)s;
  return __uint_as_float(u << 16);
}

// Build combined bf16 weight matrix Bt[col][k], col in [0,640), k in [0,128).
// col < 512: Bt[col][k] = V[b=col>>7][i=k][o=col&127]
// col >=512: Bt[col][k] = loopW[i=k][o=col-512]
__global__ void build_bt(const float* __restrict__ V, const float* __restrict__ loopW,
                         short* __restrict__ Bt)
{
  int idx = blockIdx.x * blockDim.x + threadIdx.x;
  if (idx >= 640 * 128) return;
  int col = idx >> 7;
  int k = idx & 127;
  float v;
  if (col < 512) {
    int b = col >> 7;
    int o = col & 127;
    v = V[((size_t)b * HH + k) * HH + o];
  } else {
    v = loopW[(size_t)k * HH + (col - 512)];
  }
  Bt[(size_t)col * HH + k] = f2bf(v);
}

// ---------------- CSR build ----------------

__global__ __launch_bounds__(256) void hist_deg(const int* __restrict__ dst,
                                                int* __restrict__ deg)
{
  int e = blockIdx.x * blockDim.x + threadIdx.x;
  if (e < NE) atomicAdd(&deg[dst[e]], 1);
}

// Single-block exclusive scan of deg[NN] -> rowptr[NN+1]; also rewrites deg
// with the exclusive prefix so it doubles as the scatter cursor.
__global__ __launch_bounds__(1024) void scan_deg(int* __restrict__ deg,
                                                 int* __restrict__ rowptr)
{
  __shared__ int part[1024];
  const int tid = threadIdx.x;
  const int CH = (NN + 1023) / 1024;           // 98
  const int lo = tid * CH;
  const int hi = (lo + CH < NN) ? lo + CH : NN;
  int s = 0;
  for (int i = lo; i < hi; ++i) s += deg[i];
  part[tid] = s;
  __syncthreads();
  // Hillis-Steele inclusive scan over part[]
  for (int off = 1; off < 1024; off <<= 1) {
    int t = (tid >= off) ? part[tid - off] : 0;
    __syncthreads();
    part[tid] += t;
    __syncthreads();
  }
  int run = part[tid] - s;                     // exclusive prefix for this chunk
  for (int i = lo; i < hi; ++i) {
    int d = deg[i];
    rowptr[i] = run;
    deg[i] = run;                              // cursor init
    run += d;
  }
  if (tid == 1023) rowptr[NN] = part[1023];
}

__global__ __launch_bounds__(256) void scatter_edges(
    const int* __restrict__ src, const int* __restrict__ dst, const int* __restrict__ ety,
    int* __restrict__ cursor, int* __restrict__ csr)
{
  int e = blockIdx.x * blockDim.x + threadIdx.x;
  if (e >= NE) return;
  int d = dst[e];
  int p = atomicAdd(&cursor[d], 1);
  csr[p] = src[e] | (ety[e] << 20);            // src:20 bits, ety:3 bits
}

// ---------------- GEMM ----------------
// Fused GEMM: [N,128] @ [128,640] with MFMA 16x16x32 bf16, 2 m-tiles per wave.
// Writes hb (bf16, cols 0..511) and outInit = bias + h@loopW (fp32, cols 512..639).
template<int RELU>
__global__ __launch_bounds__(256) void gemm_layer(
    const float* __restrict__ A,        // [N,128] fp32
    const short* __restrict__ Bt,       // [640][128] bf16 bits
    const float* __restrict__ bias,     // [128]
    short* __restrict__ hb,             // [N,512] bf16 bits
    float* __restrict__ outInit)        // [N,128] fp32
{
  const int wave = threadIdx.x >> 6;
  const int lane = threadIdx.x & 63;
  const int t0 = blockIdx.x * 128 + wave * 16;
  if (t0 >= NN) return;
  const int t1 = t0 + 64;
  const bool v1 = (t1 < NN);                   // NN % 16 == 0, so tiles are full
  const int r = lane & 15;                     // A row within tile / D col within tile
  const int g = lane >> 4;                     // k-group

  bf16x8 afrag0[4], afrag1[4];
  {
    const float* arow = A + (size_t)(t0 + r) * HH;
#pragma unroll
    for (int ks = 0; ks < 4; ++ks) {
      const vfloat4* ap = reinterpret_cast<const vfloat4*>(arow + ks * 32 + g * 8);
      vfloat4 x0 = ap[0], x1 = ap[1];
      bf16x8 af;
#pragma unroll
      for (int j = 0; j < 4; ++j) {
        float a0 = x0[j], a1 = x1[j];
        if (RELU) { a0 = fmaxf(a0, 0.f); a1 = fmaxf(a1, 0.f); }
        af[j] = f2bf(a0); af[j + 4] = f2bf(a1);
      }
      afrag0[ks] = af;
    }
  }
  if (v1) {
    const float* arow = A + (size_t)(t1 + r) * HH;
#pragma unroll
    for (int ks = 0; ks < 4; ++ks) {
      const vfloat4* ap = reinterpret_cast<const vfloat4*>(arow + ks * 32 + g * 8);
      vfloat4 x0 = ap[0], x1 = ap[1];
      bf16x8 af;
#pragma unroll
      for (int j = 0; j < 4; ++j) {
        float a0 = x0[j], a1 = x1[j];
        if (RELU) { a0 = fmaxf(a0, 0.f); a1 = fmaxf(a1, 0.f); }
        af[j] = f2bf(a0); af[j + 4] = f2bf(a1);
      }
      afrag1[ks] = af;
    }
  }

  const bf16x8* btv = reinterpret_cast<const bf16x8*>(Bt);
#pragma unroll 1
  for (int ct = 0; ct < 40; ++ct) {
    f32x4 acc0 = {0.f, 0.f, 0.f, 0.f};
    f32x4 acc1 = {0.f, 0.f, 0.f, 0.f};
#pragma unroll
    for (int ks = 0; ks < 4; ++ks) {
      bf16x8 bfr = btv[(size_t)(ct * 16 + r) * 16 + ks * 4 + g];
      acc0 = __builtin_amdgcn_mfma_f32_16x16x32_bf16(afrag0[ks], bfr, acc0, 0, 0, 0);
      if (v1)
        acc1 = __builtin_amdgcn_mfma_f32_16x16x32_bf16(afrag1[ks], bfr, acc1, 0, 0, 0);
    }
    // D mapping: col = lane&15 (=r), row = (lane>>4)*4 + rr  [verified]
    if (ct < 32) {
#pragma unroll
      for (int rr = 0; rr < 4; ++rr) {
        hb[(size_t)(t0 + g * 4 + rr) * 512 + ct * 16 + r] = f2bf(acc0[rr]);
        if (v1) hb[(size_t)(t1 + g * 4 + rr) * 512 + ct * 16 + r] = f2bf(acc1[rr]);
      }
    } else {
      int o = ct * 16 + r - 512;
      float bs = bias[o];
#pragma unroll
      for (int rr = 0; rr < 4; ++rr) {
        outInit[(size_t)(t0 + g * 4 + rr) * HH + o] = acc0[rr] + bs;
        if (v1) outInit[(size_t)(t1 + g * 4 + rr) * HH + o] = acc1[rr] + bs;
      }
    }
  }
}

// ---------------- Pull aggregation (no fp atomics) ----------------
// One wave per dst node: walk CSR edge list, gather hb[src] (1 KB, LLC-resident),
// accumulate with per-basis comp scale, butterfly-reduce the 4 basis groups,
// single owner-exclusive float2 RMW into out row.
__global__ __launch_bounds__(256) void aggregate(
    const int* __restrict__ rowptr, const int* __restrict__ csr,
    const float* __restrict__ comp,   // [R,B]
    const short* __restrict__ hb,     // [N,512] bf16 bits
    float* __restrict__ out)          // [N,128] fp32 (pre-initialized by GEMM)
{
  int wid = (int)(blockIdx.x * 4 + (threadIdx.x >> 6));
  wid = __builtin_amdgcn_readfirstlane(wid);   // force SGPR -> scalar loads below
  if (wid >= NN) return;
  const int lane = threadIdx.x & 63;
  const int b = lane >> 4;
  const int q = lane & 15;

  const int start = rowptr[wid];
  const int end = rowptr[wid + 1];

  float acc[8] = {0.f, 0.f, 0.f, 0.f, 0.f, 0.f, 0.f, 0.f};
  int i = start;
  for (; i + 2 <= end; i += 2) {
    int e0 = csr[i], e1 = csr[i + 1];
    const bf16x8* p0 = reinterpret_cast<const bf16x8*>(hb + (size_t)(e0 & 0xFFFFF) * 512);
    const bf16x8* p1 = reinterpret_cast<const bf16x8*>(hb + (size_t)(e1 & 0xFFFFF) * 512);
    bf16x8 h0 = p0[lane];
    bf16x8 h1 = p1[lane];
    float c0 = comp[(e0 >> 20) * NB + b];
    float c1 = comp[(e1 >> 20) * NB + b];
#pragma unroll
    for (int j = 0; j < 8; ++j) acc[j] += bf2f(h0[j]) * c0;
#pragma unroll
    for (int j = 0; j < 8; ++j) acc[j] += bf2f(h1[j]) * c1;
  }
  if (i < end) {
    int e0 = csr[i];
    const bf16x8* p0 = reinterpret_cast<const bf16x8*>(hb + (size_t)(e0 & 0xFFFFF) * 512);
    bf16x8 h0 = p0[lane];
    float c0 = comp[(e0 >> 20) * NB + b];
#pragma unroll
    for (int j = 0; j < 8; ++j) acc[j] += bf2f(h0[j]) * c0;
  }

  // reduce across the 4 basis groups (lanes xor 16, 32)
#pragma unroll
  for (int j = 0; j < 8; ++j) {
    acc[j] += __shfl_xor(acc[j], 16);
    acc[j] += __shfl_xor(acc[j], 32);
  }

  // lane writes elements o = q*8 + 2b, +1  (all 128 covered, owner-exclusive)
  vfloat2* orow = reinterpret_cast<vfloat2*>(out + (size_t)wid * HH);
  vfloat2 cur = orow[q * 4 + b];
  cur[0] += acc[2 * b];
  cur[1] += acc[2 * b + 1];
  orow[q * 4 + b] = cur;
}

extern "C" void kernel_launch(void* const* d_in, const int* in_sizes, int n_in,
                              void* d_out, int out_size, void* d_ws, size_t ws_size,
                              hipStream_t stream)
{
  const int*   srcp  = (const int*)d_in[1];
  const int*   dstp  = (const int*)d_in[2];
  const int*   etp   = (const int*)d_in[3];
  const float* emb   = (const float*)d_in[4];
  const float* V1    = (const float*)d_in[5];
  const float* comp1 = (const float*)d_in[6];
  const float* loop1 = (const float*)d_in[7];
  const float* bias1 = (const float*)d_in[8];
  const float* V2    = (const float*)d_in[9];
  const float* comp2 = (const float*)d_in[10];
  const float* loop2 = (const float*)d_in[11];
  const float* bias2 = (const float*)d_in[12];
  float* out = (float*)d_out;

  char* ws = (char*)d_ws;
  short* Bt1    = (short*)(ws);                         // 163,840 B
  short* Bt2    = (short*)(ws + 163840);                // 163,840 B
  short* hb     = (short*)(ws + 327680);                // 102,400,000 B
  float* out1   = (float*)(ws + 102727680);             // 51,200,000 B
  int*   deg    = (int*)  (ws + 153927680);             // 400,000 B (doubles as cursor)
  int*   rowptr = (int*)  (ws + 154327680);             // 400,004 B
  int*   csr    = (int*)  (ws + 154727696);             // 2,400,000 B  (total ~157.1 MB)

  const int gemm_blocks = (NN + 127) / 128;
  const int agg_blocks  = (NN + 3) / 4;
  const int e_blocks    = (NE + 255) / 256;

  // --- CSR build (once, reused by both layers) ---
  hipMemsetAsync(deg, 0, NN * sizeof(int), stream);
  hipLaunchKernelGGL(hist_deg, dim3(e_blocks), dim3(256), 0, stream, dstp, deg);
  hipLaunchKernelGGL(scan_deg, dim3(1), dim3(1024), 0, stream, deg, rowptr);
  hipLaunchKernelGGL(scatter_edges, dim3(e_blocks), dim3(256), 0, stream,
                     srcp, dstp, etp, deg, csr);

  hipLaunchKernelGGL(build_bt, dim3(320), dim3(256), 0, stream, V1, loop1, Bt1);
  hipLaunchKernelGGL(build_bt, dim3(320), dim3(256), 0, stream, V2, loop2, Bt2);

  // Layer 1
  hipLaunchKernelGGL((gemm_layer<0>), dim3(gemm_blocks), dim3(256), 0, stream,
                     emb, Bt1, bias1, hb, out1);
  hipLaunchKernelGGL(aggregate, dim3(agg_blocks), dim3(256), 0, stream,
                     rowptr, csr, comp1, hb, out1);

  // Layer 2 (relu fused into A load)
  hipLaunchKernelGGL((gemm_layer<1>), dim3(gemm_blocks), dim3(256), 0, stream,
                     out1, Bt2, bias2, hb, out);
  hipLaunchKernelGGL(aggregate, dim3(agg_blocks), dim3(256), 0, stream,
                     rowptr, csr, comp2, hb, out);
}

// Round 3
// 471.336 us; speedup vs baseline: 2.7243x; 1.4339x over previous
//
#include <hip/hip_runtime.h>
#include <hip/hip_bf16.h>

#define NN 100000
#define NE 600000
#define HH 128
#define NB 4
#define TILE 2048
#define NTILES ((NN + TILE - 1) / TILE)   // 49

typedef __attribute__((ext_vector_type(8))) short bf16x8;
typedef __attribute__((ext_vector_type(4))) float f32x4;
typedef __attribute__((ext_vector_type(4))) float vfloat4;
typedef __attribute__((ext_vector_type(2))) float vfloat2;

// round-to-nearest-even f32 -> bf16 bits (inputs are finite)
static __device__ __forceinline__ short f2bf(float f) {
  unsigned u = __float_as_uint(f);
  unsigned r = (u + 0x7fffu + ((u >> 16) & 1u)) >> 16;
  return (short)r;
}

static __device__ __forceinline__ float bf2f(short s) {
  unsigned u = (unsigned)(unsigned short)s;
  return __uint_as_float(u << 16);
}

// Build combined bf16 weight matrix Bt[col][k], col in [0,640), k in [0,128).
// col < 512: Bt[col][k] = V[b=col>>7][i=k][o=col&127]
// col >=512: Bt[col][k] = loopW[i=k][o=col-512]
__global__ void build_bt(const float* __restrict__ V, const float* __restrict__ loopW,
                         short* __restrict__ Bt)
{
  int idx = blockIdx.x * blockDim.x + threadIdx.x;
  if (idx >= 640 * 128) return;
  int col = idx >> 7;
  int k = idx & 127;
  float v;
  if (col < 512) {
    int b = col >> 7;
    int o = col & 127;
    v = V[((size_t)b * HH + k) * HH + o];
  } else {
    v = loopW[(size_t)k * HH + (col - 512)];
  }
  Bt[(size_t)col * HH + k] = f2bf(v);
}

// ---------------- CSR build ----------------

__global__ __launch_bounds__(256) void hist_deg(const int* __restrict__ dst,
                                                int* __restrict__ deg)
{
  int e = blockIdx.x * blockDim.x + threadIdx.x;
  if (e < NE) atomicAdd(&deg[dst[e]], 1);
}

// Phase 1: per-tile totals (49 blocks x 256 threads, 8 elems/thread)
__global__ __launch_bounds__(256) void scan_tiles(const int* __restrict__ deg,
                                                  int* __restrict__ tilesum)
{
  __shared__ int red[256];
  const int tid = threadIdx.x;
  int base = blockIdx.x * TILE + tid * 8;
  int s = 0;
#pragma unroll
  for (int j = 0; j < 8; ++j) {
    int i = base + j;
    if (i < NN) s += deg[i];
  }
  red[tid] = s;
  __syncthreads();
  for (int off = 128; off > 0; off >>= 1) {
    if (tid < off) red[tid] += red[tid + off];
    __syncthreads();
  }
  if (tid == 0) tilesum[blockIdx.x] = red[0];
}

// Phase 2: per-element exclusive scan = inter-tile prefix + intra-tile scan.
// Writes rowptr[i] and cursor[i] (cursor aliases deg; each thread owns its
// elements so the overwrite is race-free). Last thread writes rowptr[NN].
__global__ __launch_bounds__(256) void scan_final(const int* deg,
                                                  const int* __restrict__ tilesum,
                                                  int* __restrict__ rowptr,
                                                  int* cursor)
{
  __shared__ int lds[256];
  const int tid = threadIdx.x;
  // inter-tile exclusive prefix (broadcast loads, L2-hit, trivial)
  int pre = 0;
  for (int t = 0; t < NTILES; ++t)
    if (t < blockIdx.x) pre += tilesum[t];

  int base = blockIdx.x * TILE + tid * 8;
  int d[8];
  int s = 0;
#pragma unroll
  for (int j = 0; j < 8; ++j) {
    int i = base + j;
    d[j] = (i < NN) ? deg[i] : 0;
    s += d[j];
  }
  lds[tid] = s;
  __syncthreads();
  // Hillis-Steele inclusive scan across 256 thread sums
  for (int off = 1; off < 256; off <<= 1) {
    int t = (tid >= off) ? lds[tid - off] : 0;
    __syncthreads();
    lds[tid] += t;
    __syncthreads();
  }
  int run = pre + lds[tid] - s;   // global exclusive prefix for this thread
#pragma unroll
  for (int j = 0; j < 8; ++j) {
    int i = base + j;
    if (i < NN) {
      rowptr[i] = run;
      cursor[i] = run;
      run += d[j];
    }
  }
  if (blockIdx.x == NTILES - 1 && tid == 255)
    rowptr[NN] = pre + lds[255];
}

__global__ __launch_bounds__(256) void scatter_edges(
    const int* __restrict__ src, const int* __restrict__ dst, const int* __restrict__ ety,
    int* __restrict__ cursor, int* __restrict__ csr)
{
  int e = blockIdx.x * blockDim.x + threadIdx.x;
  if (e >= NE) return;
  int d = dst[e];
  int p = atomicAdd(&cursor[d], 1);
  csr[p] = src[e] | (ety[e] << 20);            // src:20 bits, ety:3 bits
}

// ---------------- GEMM ----------------
// Fused GEMM: [N,128] @ [128,640] with MFMA 16x16x32 bf16, 2 m-tiles per wave.
// Writes hb (bf16, cols 0..511) and outInit = bias + h@loopW (fp32, cols 512..639).
template<int RELU>
__global__ __launch_bounds__(256) void gemm_layer(
    const float* __restrict__ A,        // [N,128] fp32
    const short* __restrict__ Bt,       // [640][128] bf16 bits
    const float* __restrict__ bias,     // [128]
    short* __restrict__ hb,             // [N,512] bf16 bits
    float* __restrict__ outInit)        // [N,128] fp32
{
  const int wave = threadIdx.x >> 6;
  const int lane = threadIdx.x & 63;
  const int t0 = blockIdx.x * 128 + wave * 16;
  if (t0 >= NN) return;
  const int t1 = t0 + 64;
  const bool v1 = (t1 < NN);                   // NN % 16 == 0, so tiles are full
  const int r = lane & 15;                     // A row within tile / D col within tile
  const int g = lane >> 4;                     // k-group

  bf16x8 afrag0[4], afrag1[4];
  {
    const float* arow = A + (size_t)(t0 + r) * HH;
#pragma unroll
    for (int ks = 0; ks < 4; ++ks) {
      const vfloat4* ap = reinterpret_cast<const vfloat4*>(arow + ks * 32 + g * 8);
      vfloat4 x0 = ap[0], x1 = ap[1];
      bf16x8 af;
#pragma unroll
      for (int j = 0; j < 4; ++j) {
        float a0 = x0[j], a1 = x1[j];
        if (RELU) { a0 = fmaxf(a0, 0.f); a1 = fmaxf(a1, 0.f); }
        af[j] = f2bf(a0); af[j + 4] = f2bf(a1);
      }
      afrag0[ks] = af;
    }
  }
  if (v1) {
    const float* arow = A + (size_t)(t1 + r) * HH;
#pragma unroll
    for (int ks = 0; ks < 4; ++ks) {
      const vfloat4* ap = reinterpret_cast<const vfloat4*>(arow + ks * 32 + g * 8);
      vfloat4 x0 = ap[0], x1 = ap[1];
      bf16x8 af;
#pragma unroll
      for (int j = 0; j < 4; ++j) {
        float a0 = x0[j], a1 = x1[j];
        if (RELU) { a0 = fmaxf(a0, 0.f); a1 = fmaxf(a1, 0.f); }
        af[j] = f2bf(a0); af[j + 4] = f2bf(a1);
      }
      afrag1[ks] = af;
    }
  }

  const bf16x8* btv = reinterpret_cast<const bf16x8*>(Bt);
#pragma unroll 1
  for (int ct = 0; ct < 40; ++ct) {
    f32x4 acc0 = {0.f, 0.f, 0.f, 0.f};
    f32x4 acc1 = {0.f, 0.f, 0.f, 0.f};
#pragma unroll
    for (int ks = 0; ks < 4; ++ks) {
      bf16x8 bfr = btv[(size_t)(ct * 16 + r) * 16 + ks * 4 + g];
      acc0 = __builtin_amdgcn_mfma_f32_16x16x32_bf16(afrag0[ks], bfr, acc0, 0, 0, 0);
      if (v1)
        acc1 = __builtin_amdgcn_mfma_f32_16x16x32_bf16(afrag1[ks], bfr, acc1, 0, 0, 0);
    }
    // D mapping: col = lane&15 (=r), row = (lane>>4)*4 + rr  [verified]
    if (ct < 32) {
#pragma unroll
      for (int rr = 0; rr < 4; ++rr) {
        hb[(size_t)(t0 + g * 4 + rr) * 512 + ct * 16 + r] = f2bf(acc0[rr]);
        if (v1) hb[(size_t)(t1 + g * 4 + rr) * 512 + ct * 16 + r] = f2bf(acc1[rr]);
      }
    } else {
      int o = ct * 16 + r - 512;
      float bs = bias[o];
#pragma unroll
      for (int rr = 0; rr < 4; ++rr) {
        outInit[(size_t)(t0 + g * 4 + rr) * HH + o] = acc0[rr] + bs;
        if (v1) outInit[(size_t)(t1 + g * 4 + rr) * HH + o] = acc1[rr] + bs;
      }
    }
  }
}

// ---------------- Pull aggregation (no fp atomics) ----------------
// One wave per dst node: walk CSR edge list, gather hb[src] (1 KB, LLC-resident),
// accumulate with per-basis comp scale, butterfly-reduce the 4 basis groups,
// single owner-exclusive float2 RMW into out row.
__global__ __launch_bounds__(256) void aggregate(
    const int* __restrict__ rowptr, const int* __restrict__ csr,
    const float* __restrict__ comp,   // [R,B]
    const short* __restrict__ hb,     // [N,512] bf16 bits
    float* __restrict__ out)          // [N,128] fp32 (pre-initialized by GEMM)
{
  int wid = (int)(blockIdx.x * 4 + (threadIdx.x >> 6));
  wid = __builtin_amdgcn_readfirstlane(wid);   // force SGPR -> scalar loads below
  if (wid >= NN) return;
  const int lane = threadIdx.x & 63;
  const int b = lane >> 4;
  const int q = lane & 15;

  const int start = rowptr[wid];
  const int end = rowptr[wid + 1];

  float acc[8] = {0.f, 0.f, 0.f, 0.f, 0.f, 0.f, 0.f, 0.f};
  int i = start;
  for (; i + 2 <= end; i += 2) {
    int e0 = csr[i], e1 = csr[i + 1];
    const bf16x8* p0 = reinterpret_cast<const bf16x8*>(hb + (size_t)(e0 & 0xFFFFF) * 512);
    const bf16x8* p1 = reinterpret_cast<const bf16x8*>(hb + (size_t)(e1 & 0xFFFFF) * 512);
    bf16x8 h0 = p0[lane];
    bf16x8 h1 = p1[lane];
    float c0 = comp[(e0 >> 20) * NB + b];
    float c1 = comp[(e1 >> 20) * NB + b];
#pragma unroll
    for (int j = 0; j < 8; ++j) acc[j] += bf2f(h0[j]) * c0;
#pragma unroll
    for (int j = 0; j < 8; ++j) acc[j] += bf2f(h1[j]) * c1;
  }
  if (i < end) {
    int e0 = csr[i];
    const bf16x8* p0 = reinterpret_cast<const bf16x8*>(hb + (size_t)(e0 & 0xFFFFF) * 512);
    bf16x8 h0 = p0[lane];
    float c0 = comp[(e0 >> 20) * NB + b];
#pragma unroll
    for (int j = 0; j < 8; ++j) acc[j] += bf2f(h0[j]) * c0;
  }

  // reduce across the 4 basis groups (lanes xor 16, 32)
#pragma unroll
  for (int j = 0; j < 8; ++j) {
    acc[j] += __shfl_xor(acc[j], 16);
    acc[j] += __shfl_xor(acc[j], 32);
  }

  // lane writes elements o = q*8 + 2b, +1  (all 128 covered, owner-exclusive)
  vfloat2* orow = reinterpret_cast<vfloat2*>(out + (size_t)wid * HH);
  vfloat2 cur = orow[q * 4 + b];
  cur[0] += acc[2 * b];
  cur[1] += acc[2 * b + 1];
  orow[q * 4 + b] = cur;
}

extern "C" void kernel_launch(void* const* d_in, const int* in_sizes, int n_in,
                              void* d_out, int out_size, void* d_ws, size_t ws_size,
                              hipStream_t stream)
{
  const int*   srcp  = (const int*)d_in[1];
  const int*   dstp  = (const int*)d_in[2];
  const int*   etp   = (const int*)d_in[3];
  const float* emb   = (const float*)d_in[4];
  const float* V1    = (const float*)d_in[5];
  const float* comp1 = (const float*)d_in[6];
  const float* loop1 = (const float*)d_in[7];
  const float* bias1 = (const float*)d_in[8];
  const float* V2    = (const float*)d_in[9];
  const float* comp2 = (const float*)d_in[10];
  const float* loop2 = (const float*)d_in[11];
  const float* bias2 = (const float*)d_in[12];
  float* out = (float*)d_out;

  char* ws = (char*)d_ws;
  short* Bt1     = (short*)(ws);                         // 163,840 B
  short* Bt2     = (short*)(ws + 163840);                // 163,840 B
  short* hb      = (short*)(ws + 327680);                // 102,400,000 B
  float* out1    = (float*)(ws + 102727680);             // 51,200,000 B
  int*   deg     = (int*)  (ws + 153927680);             // 400,000 B (doubles as cursor)
  int*   rowptr  = (int*)  (ws + 154327680);             // 400,004 B
  int*   csr     = (int*)  (ws + 154727696);             // 2,400,000 B
  int*   tilesum = (int*)  (ws + 157127696);             // 196 B   (total ~157.1 MB)

  const int gemm_blocks = (NN + 127) / 128;
  const int agg_blocks  = (NN + 3) / 4;
  const int e_blocks    = (NE + 255) / 256;

  // --- CSR build (once, reused by both layers) ---
  hipMemsetAsync(deg, 0, NN * sizeof(int), stream);
  hipLaunchKernelGGL(hist_deg, dim3(e_blocks), dim3(256), 0, stream, dstp, deg);
  hipLaunchKernelGGL(scan_tiles, dim3(NTILES), dim3(256), 0, stream, deg, tilesum);
  hipLaunchKernelGGL(scan_final, dim3(NTILES), dim3(256), 0, stream,
                     deg, tilesum, rowptr, deg);
  hipLaunchKernelGGL(scatter_edges, dim3(e_blocks), dim3(256), 0, stream,
                     srcp, dstp, etp, deg, csr);

  hipLaunchKernelGGL(build_bt, dim3(320), dim3(256), 0, stream, V1, loop1, Bt1);
  hipLaunchKernelGGL(build_bt, dim3(320), dim3(256), 0, stream, V2, loop2, Bt2);

  // Layer 1
  hipLaunchKernelGGL((gemm_layer<0>), dim3(gemm_blocks), dim3(256), 0, stream,
                     emb, Bt1, bias1, hb, out1);
  hipLaunchKernelGGL(aggregate, dim3(agg_blocks), dim3(256), 0, stream,
                     rowptr, csr, comp1, hb, out1);

  // Layer 2 (relu fused into A load)
  hipLaunchKernelGGL((gemm_layer<1>), dim3(gemm_blocks), dim3(256), 0, stream,
                     out1, Bt2, bias2, hb, out);
  hipLaunchKernelGGL(aggregate, dim3(agg_blocks), dim3(256), 0, stream,
                     rowptr, csr, comp2, hb, out);
}

// Round 4
// 469.057 us; speedup vs baseline: 2.7376x; 1.0049x over previous
//
#include <hip/hip_runtime.h>
#include <hip/hip_bf16.h>

#define NN 100000
#define NE 600000
#define HH 128
#define NB 4
#define TILE 2048
#define NTILES ((NN + TILE - 1) / TILE)   // 49

typedef __attribute__((ext_vector_type(8))) short bf16x8;
typedef __attribute__((ext_vector_type(4))) float f32x4;
typedef __attribute__((ext_vector_type(4))) float vfloat4;
typedef __attribute__((ext_vector_type(2))) float vfloat2;
typedef __attribute__((ext_vector_type(4))) unsigned short ushort4v;

// round-to-nearest-even f32 -> bf16 bits (inputs are finite)
static __device__ __forceinline__ short f2bf(float f) {
  unsigned u = __float_as_uint(f);
  unsigned r = (u + 0x7fffu + ((u >> 16) & 1u)) >> 16;
  return (short)r;
}

static __device__ __forceinline__ float bf2f(short s) {
  unsigned u = (unsigned)(unsigned short)s;
  return __uint_as_float(u << 16);
}

// Build combined bf16 weight matrix Bt[col][k], col in [0,640), k in [0,128).
// col < 512: Bt[col][k] = V[b=col>>7][i=k][o=col&127]
// col >=512: Bt[col][k] = loopW[i=k][o=col-512]
__global__ void build_bt(const float* __restrict__ V, const float* __restrict__ loopW,
                         short* __restrict__ Bt)
{
  int idx = blockIdx.x * blockDim.x + threadIdx.x;
  if (idx >= 640 * 128) return;
  int col = idx >> 7;
  int k = idx & 127;
  float v;
  if (col < 512) {
    int b = col >> 7;
    int o = col & 127;
    v = V[((size_t)b * HH + k) * HH + o];
  } else {
    v = loopW[(size_t)k * HH + (col - 512)];
  }
  Bt[(size_t)col * HH + k] = f2bf(v);
}

// ---------------- CSR build ----------------

__global__ __launch_bounds__(256) void hist_deg(const int* __restrict__ dst,
                                                int* __restrict__ deg)
{
  int e = blockIdx.x * blockDim.x + threadIdx.x;
  if (e < NE) atomicAdd(&deg[dst[e]], 1);
}

// Phase 1: per-tile totals (49 blocks x 256 threads, 8 elems/thread)
__global__ __launch_bounds__(256) void scan_tiles(const int* __restrict__ deg,
                                                  int* __restrict__ tilesum)
{
  __shared__ int red[256];
  const int tid = threadIdx.x;
  int base = blockIdx.x * TILE + tid * 8;
  int s = 0;
#pragma unroll
  for (int j = 0; j < 8; ++j) {
    int i = base + j;
    if (i < NN) s += deg[i];
  }
  red[tid] = s;
  __syncthreads();
  for (int off = 128; off > 0; off >>= 1) {
    if (tid < off) red[tid] += red[tid + off];
    __syncthreads();
  }
  if (tid == 0) tilesum[blockIdx.x] = red[0];
}

// Phase 2: per-element exclusive scan = inter-tile prefix + intra-tile scan.
__global__ __launch_bounds__(256) void scan_final(const int* deg,
                                                  const int* __restrict__ tilesum,
                                                  int* __restrict__ rowptr,
                                                  int* cursor)
{
  __shared__ int lds[256];
  const int tid = threadIdx.x;
  int pre = 0;
  for (int t = 0; t < NTILES; ++t)
    if (t < blockIdx.x) pre += tilesum[t];

  int base = blockIdx.x * TILE + tid * 8;
  int d[8];
  int s = 0;
#pragma unroll
  for (int j = 0; j < 8; ++j) {
    int i = base + j;
    d[j] = (i < NN) ? deg[i] : 0;
    s += d[j];
  }
  lds[tid] = s;
  __syncthreads();
  for (int off = 1; off < 256; off <<= 1) {
    int t = (tid >= off) ? lds[tid - off] : 0;
    __syncthreads();
    lds[tid] += t;
    __syncthreads();
  }
  int run = pre + lds[tid] - s;
#pragma unroll
  for (int j = 0; j < 8; ++j) {
    int i = base + j;
    if (i < NN) {
      rowptr[i] = run;
      cursor[i] = run;
      run += d[j];
    }
  }
  if (blockIdx.x == NTILES - 1 && tid == 255)
    rowptr[NN] = pre + lds[255];
}

__global__ __launch_bounds__(256) void scatter_edges(
    const int* __restrict__ src, const int* __restrict__ dst, const int* __restrict__ ety,
    int* __restrict__ cursor, int* __restrict__ csr)
{
  int e = blockIdx.x * blockDim.x + threadIdx.x;
  if (e >= NE) return;
  int d = dst[e];
  int p = atomicAdd(&cursor[d], 1);
  csr[p] = src[e] | (ety[e] << 20);            // src:20 bits, ety:3 bits
}

// ---------------- GEMM ----------------
// Fused GEMM: [N,128] @ [128,640], MFMA 16x16x32 bf16 with SWAPPED operands:
// D^T = mfma(Bfrag, Afrag) so each lane holds 4 CONSECUTIVE output columns of
// one node row -> packed 8B/16B coalesced stores.
template<int RELU>
__global__ __launch_bounds__(256) void gemm_layer(
    const float* __restrict__ A,        // [N,128] fp32
    const short* __restrict__ Bt,       // [640][128] bf16 bits
    const float* __restrict__ bias,     // [128]
    short* __restrict__ hb,             // [N,512] bf16 bits
    float* __restrict__ outInit)        // [N,128] fp32
{
  const int wave = threadIdx.x >> 6;
  const int lane = threadIdx.x & 63;
  const int t0 = blockIdx.x * 128 + wave * 16;
  if (t0 >= NN) return;
  const int t1 = t0 + 64;
  const bool v1 = (t1 < NN);                   // NN % 16 == 0, full tiles
  const int r = lane & 15;                     // node within tile / MFMA idx
  const int g = lane >> 4;                     // k-group

  bf16x8 afrag0[4], afrag1[4];
  {
    const float* arow = A + (size_t)(t0 + r) * HH;
#pragma unroll
    for (int ks = 0; ks < 4; ++ks) {
      const vfloat4* ap = reinterpret_cast<const vfloat4*>(arow + ks * 32 + g * 8);
      vfloat4 x0 = ap[0], x1 = ap[1];
      bf16x8 af;
#pragma unroll
      for (int j = 0; j < 4; ++j) {
        float a0 = x0[j], a1 = x1[j];
        if (RELU) { a0 = fmaxf(a0, 0.f); a1 = fmaxf(a1, 0.f); }
        af[j] = f2bf(a0); af[j + 4] = f2bf(a1);
      }
      afrag0[ks] = af;
    }
  }
  if (v1) {
    const float* arow = A + (size_t)(t1 + r) * HH;
#pragma unroll
    for (int ks = 0; ks < 4; ++ks) {
      const vfloat4* ap = reinterpret_cast<const vfloat4*>(arow + ks * 32 + g * 8);
      vfloat4 x0 = ap[0], x1 = ap[1];
      bf16x8 af;
#pragma unroll
      for (int j = 0; j < 4; ++j) {
        float a0 = x0[j], a1 = x1[j];
        if (RELU) { a0 = fmaxf(a0, 0.f); a1 = fmaxf(a1, 0.f); }
        af[j] = f2bf(a0); af[j + 4] = f2bf(a1);
      }
      afrag1[ks] = af;
    }
  }

  ushort4v* hb4 = reinterpret_cast<ushort4v*>(hb);
  vfloat4* out4 = reinterpret_cast<vfloat4*>(outInit);
  const bf16x8* btv = reinterpret_cast<const bf16x8*>(Bt);
#pragma unroll 1
  for (int ct = 0; ct < 40; ++ct) {
    f32x4 acc0 = {0.f, 0.f, 0.f, 0.f};
    f32x4 acc1 = {0.f, 0.f, 0.f, 0.f};
#pragma unroll
    for (int ks = 0; ks < 4; ++ks) {
      bf16x8 bfr = btv[(size_t)(ct * 16 + r) * 16 + ks * 4 + g];
      // swapped: D^T[m=Bt col (g*4+rr), n=node (r)]
      acc0 = __builtin_amdgcn_mfma_f32_16x16x32_bf16(bfr, afrag0[ks], acc0, 0, 0, 0);
      if (v1)
        acc1 = __builtin_amdgcn_mfma_f32_16x16x32_bf16(bfr, afrag1[ks], acc1, 0, 0, 0);
    }
    // lane holds cols ct*16 + g*4 + {0..3} of node row t0+r (and t1+r)
    if (ct < 32) {
      ushort4v s0;
#pragma unroll
      for (int rr = 0; rr < 4; ++rr) s0[rr] = (unsigned short)f2bf(acc0[rr]);
      hb4[(size_t)(t0 + r) * 128 + ct * 4 + g] = s0;
      if (v1) {
        ushort4v s1;
#pragma unroll
        for (int rr = 0; rr < 4; ++rr) s1[rr] = (unsigned short)f2bf(acc1[rr]);
        hb4[(size_t)(t1 + r) * 128 + ct * 4 + g] = s1;
      }
    } else {
      vfloat4 bs = *reinterpret_cast<const vfloat4*>(bias + (ct - 32) * 16 + g * 4);
      vfloat4 o0;
#pragma unroll
      for (int rr = 0; rr < 4; ++rr) o0[rr] = acc0[rr] + bs[rr];
      out4[(size_t)(t0 + r) * 32 + (ct - 32) * 4 + g] = o0;
      if (v1) {
        vfloat4 o1;
#pragma unroll
        for (int rr = 0; rr < 4; ++rr) o1[rr] = acc1[rr] + bs[rr];
        out4[(size_t)(t1 + r) * 32 + (ct - 32) * 4 + g] = o1;
      }
    }
  }
}

// ---------------- Pull aggregation (no fp atomics) ----------------
__global__ __launch_bounds__(256) void aggregate(
    const int* __restrict__ rowptr, const int* __restrict__ csr,
    const float* __restrict__ comp,   // [R,B]
    const short* __restrict__ hb,     // [N,512] bf16 bits
    float* __restrict__ out)          // [N,128] fp32 (pre-initialized by GEMM)
{
  int wid = (int)(blockIdx.x * 4 + (threadIdx.x >> 6));
  wid = __builtin_amdgcn_readfirstlane(wid);
  if (wid >= NN) return;
  const int lane = threadIdx.x & 63;
  const int b = lane >> 4;
  const int q = lane & 15;

  const int start = rowptr[wid];
  const int end = rowptr[wid + 1];

  float acc[8] = {0.f, 0.f, 0.f, 0.f, 0.f, 0.f, 0.f, 0.f};
  int i = start;
  for (; i + 2 <= end; i += 2) {
    int e0 = csr[i], e1 = csr[i + 1];
    const bf16x8* p0 = reinterpret_cast<const bf16x8*>(hb + (size_t)(e0 & 0xFFFFF) * 512);
    const bf16x8* p1 = reinterpret_cast<const bf16x8*>(hb + (size_t)(e1 & 0xFFFFF) * 512);
    bf16x8 h0 = p0[lane];
    bf16x8 h1 = p1[lane];
    float c0 = comp[(e0 >> 20) * NB + b];
    float c1 = comp[(e1 >> 20) * NB + b];
#pragma unroll
    for (int j = 0; j < 8; ++j) acc[j] += bf2f(h0[j]) * c0;
#pragma unroll
    for (int j = 0; j < 8; ++j) acc[j] += bf2f(h1[j]) * c1;
  }
  if (i < end) {
    int e0 = csr[i];
    const bf16x8* p0 = reinterpret_cast<const bf16x8*>(hb + (size_t)(e0 & 0xFFFFF) * 512);
    bf16x8 h0 = p0[lane];
    float c0 = comp[(e0 >> 20) * NB + b];
#pragma unroll
    for (int j = 0; j < 8; ++j) acc[j] += bf2f(h0[j]) * c0;
  }

#pragma unroll
  for (int j = 0; j < 8; ++j) {
    acc[j] += __shfl_xor(acc[j], 16);
    acc[j] += __shfl_xor(acc[j], 32);
  }

  vfloat2* orow = reinterpret_cast<vfloat2*>(out + (size_t)wid * HH);
  vfloat2 cur = orow[q * 4 + b];
  cur[0] += acc[2 * b];
  cur[1] += acc[2 * b + 1];
  orow[q * 4 + b] = cur;
}

extern "C" void kernel_launch(void* const* d_in, const int* in_sizes, int n_in,
                              void* d_out, int out_size, void* d_ws, size_t ws_size,
                              hipStream_t stream)
{
  const int*   srcp  = (const int*)d_in[1];
  const int*   dstp  = (const int*)d_in[2];
  const int*   etp   = (const int*)d_in[3];
  const float* emb   = (const float*)d_in[4];
  const float* V1    = (const float*)d_in[5];
  const float* comp1 = (const float*)d_in[6];
  const float* loop1 = (const float*)d_in[7];
  const float* bias1 = (const float*)d_in[8];
  const float* V2    = (const float*)d_in[9];
  const float* comp2 = (const float*)d_in[10];
  const float* loop2 = (const float*)d_in[11];
  const float* bias2 = (const float*)d_in[12];
  float* out = (float*)d_out;

  char* ws = (char*)d_ws;
  short* Bt1     = (short*)(ws);                         // 163,840 B
  short* Bt2     = (short*)(ws + 163840);                // 163,840 B
  short* hb      = (short*)(ws + 327680);                // 102,400,000 B
  float* out1    = (float*)(ws + 102727680);             // 51,200,000 B
  int*   deg     = (int*)  (ws + 153927680);             // 400,000 B (doubles as cursor)
  int*   rowptr  = (int*)  (ws + 154327680);             // 400,004 B
  int*   csr     = (int*)  (ws + 154727696);             // 2,400,000 B
  int*   tilesum = (int*)  (ws + 157127696);             // 196 B   (total ~157.1 MB)

  const int gemm_blocks = (NN + 127) / 128;
  const int agg_blocks  = (NN + 3) / 4;
  const int e_blocks    = (NE + 255) / 256;

  // --- CSR build (once, reused by both layers) ---
  hipMemsetAsync(deg, 0, NN * sizeof(int), stream);
  hipLaunchKernelGGL(hist_deg, dim3(e_blocks), dim3(256), 0, stream, dstp, deg);
  hipLaunchKernelGGL(scan_tiles, dim3(NTILES), dim3(256), 0, stream, deg, tilesum);
  hipLaunchKernelGGL(scan_final, dim3(NTILES), dim3(256), 0, stream,
                     deg, tilesum, rowptr, deg);
  hipLaunchKernelGGL(scatter_edges, dim3(e_blocks), dim3(256), 0, stream,
                     srcp, dstp, etp, deg, csr);

  hipLaunchKernelGGL(build_bt, dim3(320), dim3(256), 0, stream, V1, loop1, Bt1);
  hipLaunchKernelGGL(build_bt, dim3(320), dim3(256), 0, stream, V2, loop2, Bt2);

  // Layer 1
  hipLaunchKernelGGL((gemm_layer<0>), dim3(gemm_blocks), dim3(256), 0, stream,
                     emb, Bt1, bias1, hb, out1);
  hipLaunchKernelGGL(aggregate, dim3(agg_blocks), dim3(256), 0, stream,
                     rowptr, csr, comp1, hb, out1);

  // Layer 2 (relu fused into A load)
  hipLaunchKernelGGL((gemm_layer<1>), dim3(gemm_blocks), dim3(256), 0, stream,
                     out1, Bt2, bias2, hb, out);
  hipLaunchKernelGGL(aggregate, dim3(agg_blocks), dim3(256), 0, stream,
                     rowptr, csr, comp2, hb, out);
}